// Round 4
// baseline (218.604 us; speedup 1.0000x reference)
//
#include <hip/hip_runtime.h>
#include <math.h>

#define NRAYS 2048
#define TOT   128
#define INDS  16
#define HID   64
#define EPSF  1e-8f
#define MTOT  (NRAYS*TOT)

typedef float f32x2 __attribute__((ext_vector_type(2)));

__device__ __forceinline__ float softplus_f(float x) {
    return fmaxf(x, 0.0f) + __logf(1.0f + __expf(-fabsf(x)));
}
__device__ __forceinline__ float sigmoid_f(float x) {
    return 1.0f / (1.0f + __expf(-x));
}
__device__ __forceinline__ float tanh_fast(float x) {
    float e2 = __expf(2.0f * x);
    return 1.0f - 2.0f / (e2 + 1.0f);
}
__device__ __forceinline__ f32x2 pkmax(f32x2 a, f32x2 b) {
    f32x2 r; r.x = fmaxf(a.x, b.x); r.y = fmaxf(a.y, b.y); return r;
}

// Build the 8 jittered z samples for this half (kbase = 0 or 8).
#define MAKE_Z(jp, kbase, nears, span)                                        \
    const float4* jp4 = (const float4*)(jp);                                  \
    float4 jA = jp4[0], jB = jp4[1];                                          \
    float s16 = (span) * (1.0f/16.0f);                                        \
    float hs16 = 0.5f * s16;                                                  \
    f32x2 z01, z23, z45, z67;                                                 \
    z01.x = fmaf(jA.x, s16, fmaf((float)((kbase)+0)*(1.0f/15.0f), span, nears) - hs16); \
    z01.y = fmaf(jA.y, s16, fmaf((float)((kbase)+1)*(1.0f/15.0f), span, nears) - hs16); \
    z23.x = fmaf(jA.z, s16, fmaf((float)((kbase)+2)*(1.0f/15.0f), span, nears) - hs16); \
    z23.y = fmaf(jA.w, s16, fmaf((float)((kbase)+3)*(1.0f/15.0f), span, nears) - hs16); \
    z45.x = fmaf(jB.x, s16, fmaf((float)((kbase)+4)*(1.0f/15.0f), span, nears) - hs16); \
    z45.y = fmaf(jB.y, s16, fmaf((float)((kbase)+5)*(1.0f/15.0f), span, nears) - hs16); \
    z67.x = fmaf(jB.z, s16, fmaf((float)((kbase)+6)*(1.0f/15.0f), span, nears) - hs16); \
    z67.y = fmaf(jB.w, s16, fmaf((float)((kbase)+7)*(1.0f/15.0f), span, nears) - hs16);

// Shared inner body given A2/B2 already formed (A,B pre-scaled by 1/2pi).
#define DENSITY_J_BODY(A2, B2)                                                \
    {                                                                         \
        f32x2 g01 = z01*(B2) + (A2);                                          \
        f32x2 g23 = z23*(B2) + (A2);                                          \
        f32x2 g45 = z45*(B2) + (A2);                                          \
        f32x2 g67 = z67*(B2) + (A2);                                          \
        f32x2 h01, h23, h45, h67;                                             \
        h01.x = __builtin_amdgcn_sinf(g01.x); h01.y = __builtin_amdgcn_sinf(g01.y); \
        h23.x = __builtin_amdgcn_sinf(g23.x); h23.y = __builtin_amdgcn_sinf(g23.y); \
        h45.x = __builtin_amdgcn_sinf(g45.x); h45.y = __builtin_amdgcn_sinf(g45.y); \
        h67.x = __builtin_amdgcn_sinf(g67.x); h67.y = __builtin_amdgcn_sinf(g67.y); \
        float w20 = Wd2[3*j], w21 = Wd2[3*j+1], w22 = Wd2[3*j+2];             \
        f32x2 W0 = {w20,w20}, W1 = {w21,w21}, W2 = {w22,w22};                 \
        a0_01 += h01*W0; a0_23 += h23*W0; a0_45 += h45*W0; a0_67 += h67*W0;   \
        a1_01 += h01*W1; a1_23 += h23*W1; a1_45 += h45*W1; a1_67 += h67*W1;   \
        a2_01 += h01*W2; a2_23 += h23*W2; a2_45 += h45*W2; a2_67 += h67*W2;   \
    }

#define DENSITY_EPILOG(mx0o, mx1o, mx2o)                                      \
    {                                                                         \
        f32x2 p0 = pkmax(pkmax(a0_01, a0_23), pkmax(a0_45, a0_67));           \
        f32x2 p1 = pkmax(pkmax(a1_01, a1_23), pkmax(a1_45, a1_67));           \
        f32x2 p2 = pkmax(pkmax(a2_01, a2_23), pkmax(a2_45, a2_67));           \
        mx0o = fmaxf(p0.x, p0.y);                                             \
        mx1o = fmaxf(p1.x, p1.y);                                             \
        mx2o = fmaxf(p2.x, p2.y);                                             \
    }

#define DECL_ACC                                                              \
    f32x2 a0_01 = {0.f,0.f}, a0_23 = {0.f,0.f}, a0_45 = {0.f,0.f}, a0_67 = {0.f,0.f}; \
    f32x2 a1_01 = {0.f,0.f}, a1_23 = {0.f,0.f}, a1_45 = {0.f,0.f}, a1_67 = {0.f,0.f}; \
    f32x2 a2_01 = {0.f,0.f}, a2_23 = {0.f,0.f}, a2_45 = {0.f,0.f}, a2_67 = {0.f,0.f};

// Depth-0 density: A,B from LDS (block-uniform geometry precomputed once).
__device__ __forceinline__ void density_max3_half_lds(
    const float2* __restrict__ sAB,
    float nears, float span, const float* __restrict__ jp, int kbase,
    const float* __restrict__ Wd2,
    float& mx0o, float& mx1o, float& mx2o)
{
    MAKE_Z(jp, kbase, nears, span)
    DECL_ACC
    #pragma unroll 2
    for (int j = 0; j < HID; ++j) {
        float2 AB = sAB[j];                 // ds_read_b64, broadcast
        f32x2 A2 = {AB.x, AB.x}, B2 = {AB.y, AB.y};
        DENSITY_J_BODY(A2, B2)
    }
    DENSITY_EPILOG(mx0o, mx1o, mx2o)
}

// Depth-1 density: o,d diverge per sub-ray -> compute A,B inline.
__device__ __forceinline__ void density_max3_half(
    float ox, float oy, float oz, float dx, float dy, float dz,
    float nears, float span, const float* __restrict__ jp, int kbase,
    const float* __restrict__ Wd1, const float* __restrict__ Wd2,
    float& mx0o, float& mx1o, float& mx2o)
{
    MAKE_Z(jp, kbase, nears, span)
    DECL_ACC
    const float INV2PI = 0.15915494309189535f;
    #pragma unroll 2
    for (int j = 0; j < HID; ++j) {
        float w1x = Wd1[j], w1y = Wd1[HID+j], w1z = Wd1[2*HID+j];
        float A = (ox*w1x + oy*w1y + oz*w1z) * INV2PI;
        float B = (dx*w1x + dy*w1y + dz*w1z) * INV2PI;
        f32x2 A2 = {A, A}, B2 = {B, B};
        DENSITY_J_BODY(A2, B2)
    }
    DENSITY_EPILOG(mx0o, mx1o, mx2o)
}

__device__ __forceinline__ void env_logv(
    const float* __restrict__ env_map,
    float px, float py, float pz,
    float& v0, float& v1, float& v2)
{
    float theta = atan2f(px, -pz) * (1.0f/3.14159265358979323846f);
    float acv = (fabsf(py) <= 1.0f) ? acosf(py) : 0.0f;  // nan_to_num(arccos)
    float phi = 0.63661977236758134308f * acv - 1.0f;    // 2/pi
    float ixf = ((theta + 1.0f)*256.0f - 1.0f)*0.5f;
    float iyf = ((phi   + 1.0f)*128.0f - 1.0f)*0.5f;
    float x0f = floorf(ixf), y0f = floorf(iyf);
    float wx = ixf - x0f, wy = iyf - y0f;
    v0 = 0.f; v1 = 0.f; v2 = 0.f;
    auto tap = [&](float xc, float yc, float w) {
        if (xc >= 0.0f && xc < 256.0f && yc >= 0.0f && yc < 128.0f) {
            int xi = (int)xc, yi = (int)yc;
            const float* e = env_map + yi*256 + xi;
            v0 += w * e[0];
            v1 += w * e[128*256];
            v2 += w * e[2*128*256];
        }
    };
    tap(x0f,      y0f,      (1.0f-wx)*(1.0f-wy));
    tap(x0f+1.0f, y0f,      wx*(1.0f-wy));
    tap(x0f,      y0f+1.0f, (1.0f-wx)*wy);
    tap(x0f+1.0f, y0f+1.0f, wx*wy);
}

// 256 threads/block = 1 ray; lane pair (2s,2s+1) shares sub-ray s.
// __launch_bounds__(256,6): 6 waves/SIMD -> VGPR budget ~85. r3's (256,8)
// forced a 64-reg budget, the allocator crushed to 32 and spilled 3.7 MB
// to scratch. 85 regs fits the ~60-reg live set spill-free at 24 waves/CU.
__global__ __launch_bounds__(256, 6)
void render_kernel(const float* __restrict__ rays_o,
                   const float* __restrict__ rays_d,
                   const float* __restrict__ env_map,
                   const float* __restrict__ Wd1,
                   const float* __restrict__ Wd2,
                   const float* __restrict__ Wf1,
                   const float* __restrict__ Ws,
                   const float* __restrict__ Wdir,
                   const float* __restrict__ Wrho,
                   const float* __restrict__ jitter,
                   const float* __restrict__ u_t,
                   const float* __restrict__ u_scatter,
                   const int*   __restrict__ channel,
                   float* __restrict__ out)
{
    const int ray  = blockIdx.x;
    const int tid  = threadIdx.x;
    const int s    = tid >> 1;
    const int half = tid & 1;
    const int m    = ray * TOT + s;
    const int kbase = half * 8;

    __shared__ float2 sAB[HID];
    __shared__ float  sred[4][3];

    float ox = rays_o[ray*3+0], oy = rays_o[ray*3+1], oz = rays_o[ray*3+2];
    float dx = rays_d[ray*3+0], dy = rays_d[ray*3+1], dz = rays_d[ray*3+2];

    // ---- depth-0 A,B precompute (o,d block-uniform) ----
    if (tid < HID) {
        const float INV2PI = 0.15915494309189535f;
        float w1x = Wd1[tid], w1y = Wd1[HID+tid], w1z = Wd1[2*HID+tid];
        float A = (ox*w1x + oy*w1y + oz*w1z) * INV2PI;
        float B = (dx*w1x + dy*w1y + dz*w1z) * INV2PI;
        sAB[tid] = make_float2(A, B);
    }
    __syncthreads();

    float thr0 = 1.f, thr1 = 1.f, thr2 = 1.f;
    float rgb0 = 0.f, rgb1 = 0.f, rgb2 = 0.f;
    bool alive;

    // ================= depth 0 =================
    {
        float a = dx*dx + dy*dy + dz*dz;
        float b = 2.0f*(dx*ox + dy*oy + dz*oz);
        float c = (ox*ox + oy*oy + oz*oz) - 1.0f;
        float delta = b*b - 4.0f*a*c;
        alive = (delta > 0.0f);
        if (alive) {
            float sq    = sqrtf(delta);
            float nears = fmaxf((-b - sq) / (2.0f*a), 0.001f);
            float fars  = fmaxf((-b + sq) / (2.0f*a), 0.001f);
            float span  = fars - nears;

            float mx0, mx1, mx2;
            density_max3_half_lds(sAB, nears, span,
                                  jitter + (size_t)m*INDS + kbase, kbase,
                                  Wd2, mx0,mx1,mx2);
            mx0 = fmaxf(mx0, __shfl_xor(mx0, 1, 64));
            mx1 = fmaxf(mx1, __shfl_xor(mx1, 1, 64));
            mx2 = fmaxf(mx2, __shfl_xor(mx2, 1, 64));

            float maj0 = fmaxf(softplus_f(mx0), 0.001f);
            float maj1 = fmaxf(softplus_f(mx1), 0.001f);
            float maj2 = fmaxf(softplus_f(mx2), 0.001f);
            float mmax = fmaxf(fmaxf(maj0, maj1), maj2);

            int   ch  = channel[m];
            float maj = (ch == 0) ? maj0 : ((ch == 1) ? maj1 : maj2);
            float t   = -log1pf(-u_t[m]) / maj + nears;

            if (t >= fars) {
                float den0 = __expf(-maj0*span)/(mmax+EPSF) + EPSF;
                float den1 = __expf(-maj1*span)/(mmax+EPSF) + EPSF;
                float den2 = __expf(-maj2*span)/(mmax+EPSF) + EPSF;
                float idm = 3.0f / (den0+den1+den2);
                float v0,v1,v2;
                env_logv(env_map, fmaf(dx,fars,ox), fmaf(dy,fars,oy), fmaf(dz,fars,oz), v0,v1,v2);
                rgb0 = den0*idm*__expf(v0);
                rgb1 = den1*idm*__expf(v1);
                rgb2 = den2*idm*__expf(v2);
                alive = false;
            } else {
                float tn  = t - nears;
                float imm = 1.0f / mmax;
                float tr0 = __expf(-maj0*tn) * imm;
                float tr1 = __expf(-maj1*tn) * imm;
                float tr2 = __expf(-maj2*tn) * imm;
                float i2m = 3.0f / (maj0*tr0 + maj1*tr1 + maj2*tr2);
                thr0 = tr0 * i2m;   // thr was 1
                thr1 = tr1 * i2m;
                thr2 = tr2 * i2m;
                ox = fmaf(dx, t, ox); oy = fmaf(dy, t, oy); oz = fmaf(dz, t, oz);

                // material MLP, hidden dim split across the lane pair
                float st0=0.f, st1=0.f, st2=0.f;
                float dn0=0.f, dn1=0.f, dn2v=0.f;
                float rh0=0.f, rh1=0.f, rh2=0.f;
                const int j0 = half * 32;
                #pragma unroll 2
                for (int j = j0; j < j0 + 32; ++j) {
                    float pre = ox*Wf1[j] + oy*Wf1[HID+j] + oz*Wf1[2*HID+j]
                              + dx*Wf1[3*HID+j] + dy*Wf1[4*HID+j] + dz*Wf1[5*HID+j];
                    float f = tanh_fast(pre);
                    st0  = fmaf(f, Ws[j*3+0], st0);
                    st1  = fmaf(f, Ws[j*3+1], st1);
                    st2  = fmaf(f, Ws[j*3+2], st2);
                    dn0  = fmaf(f, Wdir[j*3+0], dn0);
                    dn1  = fmaf(f, Wdir[j*3+1], dn1);
                    dn2v = fmaf(f, Wdir[j*3+2], dn2v);
                    rh0  = fmaf(f, Wrho[j*3+0], rh0);
                    rh1  = fmaf(f, Wrho[j*3+1], rh1);
                    rh2  = fmaf(f, Wrho[j*3+2], rh2);
                }
                st0  += __shfl_xor(st0, 1, 64);
                st1  += __shfl_xor(st1, 1, 64);
                st2  += __shfl_xor(st2, 1, 64);
                dn0  += __shfl_xor(dn0, 1, 64);
                dn1  += __shfl_xor(dn1, 1, 64);
                dn2v += __shfl_xor(dn2v, 1, 64);
                rh0  += __shfl_xor(rh0, 1, 64);
                rh1  += __shfl_xor(rh1, 1, 64);
                rh2  += __shfl_xor(rh2, 1, 64);

                float stch = (ch == 0) ? st0 : ((ch == 1) ? st1 : st2);
                float sp = fminf(softplus_f(stch) / maj, 1.0f);
                if (u_scatter[m] < sp) {
                    float inr = 1.0f / (sqrtf(dn0*dn0 + dn1*dn1 + dn2v*dn2v) + EPSF);
                    dx = dn0*inr; dy = dn1*inr; dz = dn2v*inr;
                    float isp = 1.0f/(sp + EPSF);
                    thr0 *= isp * sigmoid_f(rh0);
                    thr1 *= isp * sigmoid_f(rh1);
                    thr2 *= isp * sigmoid_f(rh2);
                } else {
                    float iv = 1.0f/(1.0f - sp + EPSF);
                    thr0 *= iv; thr1 *= iv; thr2 *= iv;
                }
            }
        }
    }

    // ================= depth 1 (t = fars -> hit if delta>0) =================
    if (alive) {
        float a = dx*dx + dy*dy + dz*dz;
        float b = 2.0f*(dx*ox + dy*oy + dz*oz);
        float c = (ox*ox + oy*oy + oz*oz) - 1.0f;
        float delta = b*b - 4.0f*a*c;
        if (delta > 0.0f) {
            float sq    = sqrtf(delta);
            float nears = fmaxf((-b - sq) / (2.0f*a), 0.001f);
            float fars  = fmaxf((-b + sq) / (2.0f*a), 0.001f);
            float span  = fars - nears;

            float mx0, mx1, mx2;
            density_max3_half(ox,oy,oz, dx,dy,dz, nears, span,
                              jitter + ((size_t)MTOT + m)*INDS + kbase, kbase,
                              Wd1, Wd2, mx0,mx1,mx2);
            mx0 = fmaxf(mx0, __shfl_xor(mx0, 1, 64));
            mx1 = fmaxf(mx1, __shfl_xor(mx1, 1, 64));
            mx2 = fmaxf(mx2, __shfl_xor(mx2, 1, 64));

            float maj0 = fmaxf(softplus_f(mx0), 0.001f);
            float maj1 = fmaxf(softplus_f(mx1), 0.001f);
            float maj2 = fmaxf(softplus_f(mx2), 0.001f);
            float mmax = fmaxf(fmaxf(maj0, maj1), maj2);

            float den0 = __expf(-maj0*span)/(mmax+EPSF) + EPSF;
            float den1 = __expf(-maj1*span)/(mmax+EPSF) + EPSF;
            float den2 = __expf(-maj2*span)/(mmax+EPSF) + EPSF;
            float idm = 3.0f / (den0+den1+den2);
            float v0,v1,v2;
            env_logv(env_map, fmaf(dx,fars,ox), fmaf(dy,fars,oy), fmaf(dz,fars,oz), v0,v1,v2);
            rgb0 += thr0 * den0*idm*__expf(v0);
            rgb1 += thr1 * den1*idm*__expf(v1);
            rgb2 += thr2 * den2*idm*__expf(v2);
        }
    }

    // ---- reduction: each sub-ray duplicated x2 -> sum/256 == mean/128 ----
    float r0 = rgb0, r1 = rgb1, r2 = rgb2;
    #pragma unroll
    for (int off = 32; off > 0; off >>= 1) {
        r0 += __shfl_down(r0, off, 64);
        r1 += __shfl_down(r1, off, 64);
        r2 += __shfl_down(r2, off, 64);
    }
    int wave = tid >> 6;
    if ((tid & 63) == 0) {
        sred[wave][0] = r0; sred[wave][1] = r1; sred[wave][2] = r2;
    }
    __syncthreads();
    if (tid == 0) {
        out[ray*3+0] = (sred[0][0]+sred[1][0]+sred[2][0]+sred[3][0]) * (1.0f/256.0f);
        out[ray*3+1] = (sred[0][1]+sred[1][1]+sred[2][1]+sred[3][1]) * (1.0f/256.0f);
        out[ray*3+2] = (sred[0][2]+sred[1][2]+sred[2][2]+sred[3][2]) * (1.0f/256.0f);
    }
}

extern "C" void kernel_launch(void* const* d_in, const int* in_sizes, int n_in,
                              void* d_out, int out_size, void* d_ws, size_t ws_size,
                              hipStream_t stream) {
    const float* rays_o    = (const float*)d_in[0];
    const float* rays_d    = (const float*)d_in[1];
    const float* env_map   = (const float*)d_in[2];
    const float* Wd1       = (const float*)d_in[3];
    const float* Wd2       = (const float*)d_in[4];
    const float* Wf1       = (const float*)d_in[5];
    const float* Ws        = (const float*)d_in[6];
    const float* Wdir      = (const float*)d_in[7];
    const float* Wrho      = (const float*)d_in[8];
    const float* jitter    = (const float*)d_in[9];
    const float* u_t       = (const float*)d_in[10];
    const float* u_scatter = (const float*)d_in[11];
    const int*   channel   = (const int*)d_in[12];
    float* out = (float*)d_out;

    render_kernel<<<dim3(NRAYS), dim3(256), 0, stream>>>(
        rays_o, rays_d, env_map, Wd1, Wd2, Wf1, Ws, Wdir, Wrho,
        jitter, u_t, u_scatter, channel, out);
}

// Round 5
// 216.501 us; speedup vs baseline: 1.0097x; 1.0097x over previous
//
#include <hip/hip_runtime.h>
#include <math.h>

#define NRAYS 2048
#define TOT   128
#define INDS  16
#define HID   64
#define EPSF  1e-8f
#define MTOT  (NRAYS*TOT)

typedef float f32x2 __attribute__((ext_vector_type(2)));

__device__ __forceinline__ float softplus_f(float x) {
    return fmaxf(x, 0.0f) + __logf(1.0f + __expf(-fabsf(x)));
}
__device__ __forceinline__ float sigmoid_f(float x) {
    return 1.0f / (1.0f + __expf(-x));
}
__device__ __forceinline__ float tanh_fast(float x) {
    float e2 = __expf(2.0f * x);
    return 1.0f - 2.0f / (e2 + 1.0f);
}
__device__ __forceinline__ f32x2 pkmax(f32x2 a, f32x2 b) {
    f32x2 r; r.x = fmaxf(a.x, b.x); r.y = fmaxf(a.y, b.y); return r;
}

// Build the 8 jittered z samples for this half (kbase = 0 or 8).
#define MAKE_Z(jp, kbase, nears, span)                                        \
    const float4* jp4 = (const float4*)(jp);                                  \
    float4 jA = jp4[0], jB = jp4[1];                                          \
    float s16 = (span) * (1.0f/16.0f);                                        \
    float hs16 = 0.5f * s16;                                                  \
    f32x2 z01, z23, z45, z67;                                                 \
    z01.x = fmaf(jA.x, s16, fmaf((float)((kbase)+0)*(1.0f/15.0f), span, nears) - hs16); \
    z01.y = fmaf(jA.y, s16, fmaf((float)((kbase)+1)*(1.0f/15.0f), span, nears) - hs16); \
    z23.x = fmaf(jA.z, s16, fmaf((float)((kbase)+2)*(1.0f/15.0f), span, nears) - hs16); \
    z23.y = fmaf(jA.w, s16, fmaf((float)((kbase)+3)*(1.0f/15.0f), span, nears) - hs16); \
    z45.x = fmaf(jB.x, s16, fmaf((float)((kbase)+4)*(1.0f/15.0f), span, nears) - hs16); \
    z45.y = fmaf(jB.y, s16, fmaf((float)((kbase)+5)*(1.0f/15.0f), span, nears) - hs16); \
    z67.x = fmaf(jB.z, s16, fmaf((float)((kbase)+6)*(1.0f/15.0f), span, nears) - hs16); \
    z67.y = fmaf(jB.w, s16, fmaf((float)((kbase)+7)*(1.0f/15.0f), span, nears) - hs16);

// Inner body given A,B (pre-scaled by 1/2pi) and the 3 Wd2 weights.
#define DENSITY_J_BODY(Af, Bf, w20, w21, w22)                                 \
    {                                                                         \
        f32x2 A2 = {(Af),(Af)}, B2 = {(Bf),(Bf)};                             \
        f32x2 g01 = z01*B2 + A2;                                              \
        f32x2 g23 = z23*B2 + A2;                                              \
        f32x2 g45 = z45*B2 + A2;                                              \
        f32x2 g67 = z67*B2 + A2;                                              \
        f32x2 h01, h23, h45, h67;                                             \
        h01.x = __builtin_amdgcn_sinf(g01.x); h01.y = __builtin_amdgcn_sinf(g01.y); \
        h23.x = __builtin_amdgcn_sinf(g23.x); h23.y = __builtin_amdgcn_sinf(g23.y); \
        h45.x = __builtin_amdgcn_sinf(g45.x); h45.y = __builtin_amdgcn_sinf(g45.y); \
        h67.x = __builtin_amdgcn_sinf(g67.x); h67.y = __builtin_amdgcn_sinf(g67.y); \
        f32x2 W0 = {(w20),(w20)}, W1 = {(w21),(w21)}, W2 = {(w22),(w22)};     \
        a0_01 += h01*W0; a0_23 += h23*W0; a0_45 += h45*W0; a0_67 += h67*W0;   \
        a1_01 += h01*W1; a1_23 += h23*W1; a1_45 += h45*W1; a1_67 += h67*W1;   \
        a2_01 += h01*W2; a2_23 += h23*W2; a2_45 += h45*W2; a2_67 += h67*W2;   \
    }

#define DENSITY_EPILOG(mx0o, mx1o, mx2o)                                      \
    {                                                                         \
        f32x2 p0 = pkmax(pkmax(a0_01, a0_23), pkmax(a0_45, a0_67));           \
        f32x2 p1 = pkmax(pkmax(a1_01, a1_23), pkmax(a1_45, a1_67));           \
        f32x2 p2 = pkmax(pkmax(a2_01, a2_23), pkmax(a2_45, a2_67));           \
        mx0o = fmaxf(p0.x, p0.y);                                             \
        mx1o = fmaxf(p1.x, p1.y);                                             \
        mx2o = fmaxf(p2.x, p2.y);                                             \
    }

#define DECL_ACC                                                              \
    f32x2 a0_01 = {0.f,0.f}, a0_23 = {0.f,0.f}, a0_45 = {0.f,0.f}, a0_67 = {0.f,0.f}; \
    f32x2 a1_01 = {0.f,0.f}, a1_23 = {0.f,0.f}, a1_45 = {0.f,0.f}, a1_67 = {0.f,0.f}; \
    f32x2 a2_01 = {0.f,0.f}, a2_23 = {0.f,0.f}, a2_45 = {0.f,0.f}, a2_67 = {0.f,0.f};

// LDS table: 8 floats per j. q0={A,B,w20,w21}, q1={w22, w1x/2pi, w1y/2pi, w1z/2pi}
// Hot loops read ONLY LDS (ds completes in-order -> compiler emits fine
// lgkmcnt(N) pipelining). r4's regression: ds_read + s_load(Wd2) mixed in one
// loop -> SMEM/DS out-of-order completion forces lgkmcnt(0) drains per iter.

// Depth-0 density: A,B read directly from LDS.
__device__ __forceinline__ void density_max3_half_d0(
    const float* __restrict__ sT,
    float nears, float span, const float* __restrict__ jp, int kbase,
    float& mx0o, float& mx1o, float& mx2o)
{
    MAKE_Z(jp, kbase, nears, span)
    DECL_ACC
    #pragma unroll 4
    for (int j = 0; j < HID; ++j) {
        const float4* p = (const float4*)&sT[j*8];
        float4 q0 = p[0];
        float4 q1 = p[1];
        DENSITY_J_BODY(q0.x, q0.y, q0.z, q0.w, q1.x)
    }
    DENSITY_EPILOG(mx0o, mx1o, mx2o)
}

// Depth-1 density: o,d diverge -> A,B from pre-scaled w1 in LDS (6 fma).
__device__ __forceinline__ void density_max3_half_d1(
    const float* __restrict__ sT,
    float ox, float oy, float oz, float dx, float dy, float dz,
    float nears, float span, const float* __restrict__ jp, int kbase,
    float& mx0o, float& mx1o, float& mx2o)
{
    MAKE_Z(jp, kbase, nears, span)
    DECL_ACC
    #pragma unroll 4
    for (int j = 0; j < HID; ++j) {
        const float4* p = (const float4*)&sT[j*8];
        float4 q0 = p[0];
        float4 q1 = p[1];
        float A = ox*q1.y + oy*q1.z + oz*q1.w;
        float B = dx*q1.y + dy*q1.z + dz*q1.w;
        DENSITY_J_BODY(A, B, q0.z, q0.w, q1.x)
    }
    DENSITY_EPILOG(mx0o, mx1o, mx2o)
}

__device__ __forceinline__ void env_logv(
    const float* __restrict__ env_map,
    float px, float py, float pz,
    float& v0, float& v1, float& v2)
{
    float theta = atan2f(px, -pz) * (1.0f/3.14159265358979323846f);
    float acv = (fabsf(py) <= 1.0f) ? acosf(py) : 0.0f;  // nan_to_num(arccos)
    float phi = 0.63661977236758134308f * acv - 1.0f;    // 2/pi
    float ixf = ((theta + 1.0f)*256.0f - 1.0f)*0.5f;
    float iyf = ((phi   + 1.0f)*128.0f - 1.0f)*0.5f;
    float x0f = floorf(ixf), y0f = floorf(iyf);
    float wx = ixf - x0f, wy = iyf - y0f;
    v0 = 0.f; v1 = 0.f; v2 = 0.f;
    auto tap = [&](float xc, float yc, float w) {
        if (xc >= 0.0f && xc < 256.0f && yc >= 0.0f && yc < 128.0f) {
            int xi = (int)xc, yi = (int)yc;
            const float* e = env_map + yi*256 + xi;
            v0 += w * e[0];
            v1 += w * e[128*256];
            v2 += w * e[2*128*256];
        }
    };
    tap(x0f,      y0f,      (1.0f-wx)*(1.0f-wy));
    tap(x0f+1.0f, y0f,      wx*(1.0f-wy));
    tap(x0f,      y0f+1.0f, (1.0f-wx)*wy);
    tap(x0f+1.0f, y0f+1.0f, wx*wy);
}

// 256 threads/block = 1 ray; lane pair (2s,2s+1) shares sub-ray s.
// (256,8): 64-VGPR budget; r4 proved the LDS-table live set is ~40 regs,
// so this should NOT spill (watch WRITE_SIZE: ~80 KB good, MBs = spill).
__global__ __launch_bounds__(256, 8)
void render_kernel(const float* __restrict__ rays_o,
                   const float* __restrict__ rays_d,
                   const float* __restrict__ env_map,
                   const float* __restrict__ Wd1,
                   const float* __restrict__ Wd2,
                   const float* __restrict__ Wf1,
                   const float* __restrict__ Ws,
                   const float* __restrict__ Wdir,
                   const float* __restrict__ Wrho,
                   const float* __restrict__ jitter,
                   const float* __restrict__ u_t,
                   const float* __restrict__ u_scatter,
                   const int*   __restrict__ channel,
                   float* __restrict__ out)
{
    const int ray  = blockIdx.x;
    const int tid  = threadIdx.x;
    const int s    = tid >> 1;
    const int half = tid & 1;
    const int m    = ray * TOT + s;
    const int kbase = half * 8;

    __shared__ float sT[HID*8];
    __shared__ float sred[4][3];

    float ox = rays_o[ray*3+0], oy = rays_o[ray*3+1], oz = rays_o[ray*3+2];
    float dx = rays_d[ray*3+0], dy = rays_d[ray*3+1], dz = rays_d[ray*3+2];

    // ---- per-block table: A,B (block-uniform depth-0 geometry) + weights ----
    if (tid < HID) {
        const float INV2PI = 0.15915494309189535f;
        float w1x = Wd1[tid], w1y = Wd1[HID+tid], w1z = Wd1[2*HID+tid];
        float pw1x = w1x*INV2PI, pw1y = w1y*INV2PI, pw1z = w1z*INV2PI;
        float A = ox*pw1x + oy*pw1y + oz*pw1z;
        float B = dx*pw1x + dy*pw1y + dz*pw1z;
        float* p = &sT[tid*8];
        p[0] = A;            p[1] = B;
        p[2] = Wd2[3*tid];   p[3] = Wd2[3*tid+1];
        p[4] = Wd2[3*tid+2];
        p[5] = pw1x;         p[6] = pw1y;        p[7] = pw1z;
    }
    __syncthreads();

    float thr0 = 1.f, thr1 = 1.f, thr2 = 1.f;
    float rgb0 = 0.f, rgb1 = 0.f, rgb2 = 0.f;
    bool alive;

    // ================= depth 0 =================
    {
        float a = dx*dx + dy*dy + dz*dz;
        float b = 2.0f*(dx*ox + dy*oy + dz*oz);
        float c = (ox*ox + oy*oy + oz*oz) - 1.0f;
        float delta = b*b - 4.0f*a*c;
        alive = (delta > 0.0f);
        if (alive) {
            float sq    = sqrtf(delta);
            float nears = fmaxf((-b - sq) / (2.0f*a), 0.001f);
            float fars  = fmaxf((-b + sq) / (2.0f*a), 0.001f);
            float span  = fars - nears;

            float mx0, mx1, mx2;
            density_max3_half_d0(sT, nears, span,
                                 jitter + (size_t)m*INDS + kbase, kbase,
                                 mx0,mx1,mx2);
            mx0 = fmaxf(mx0, __shfl_xor(mx0, 1, 64));
            mx1 = fmaxf(mx1, __shfl_xor(mx1, 1, 64));
            mx2 = fmaxf(mx2, __shfl_xor(mx2, 1, 64));

            float maj0 = fmaxf(softplus_f(mx0), 0.001f);
            float maj1 = fmaxf(softplus_f(mx1), 0.001f);
            float maj2 = fmaxf(softplus_f(mx2), 0.001f);
            float mmax = fmaxf(fmaxf(maj0, maj1), maj2);

            int   ch  = channel[m];
            float maj = (ch == 0) ? maj0 : ((ch == 1) ? maj1 : maj2);
            float t   = -log1pf(-u_t[m]) / maj + nears;

            if (t >= fars) {
                float den0 = __expf(-maj0*span)/(mmax+EPSF) + EPSF;
                float den1 = __expf(-maj1*span)/(mmax+EPSF) + EPSF;
                float den2 = __expf(-maj2*span)/(mmax+EPSF) + EPSF;
                float idm = 3.0f / (den0+den1+den2);
                float v0,v1,v2;
                env_logv(env_map, fmaf(dx,fars,ox), fmaf(dy,fars,oy), fmaf(dz,fars,oz), v0,v1,v2);
                rgb0 = den0*idm*__expf(v0);
                rgb1 = den1*idm*__expf(v1);
                rgb2 = den2*idm*__expf(v2);
                alive = false;
            } else {
                float tn  = t - nears;
                float imm = 1.0f / mmax;
                float tr0 = __expf(-maj0*tn) * imm;
                float tr1 = __expf(-maj1*tn) * imm;
                float tr2 = __expf(-maj2*tn) * imm;
                float i2m = 3.0f / (maj0*tr0 + maj1*tr1 + maj2*tr2);
                thr0 = tr0 * i2m;   // thr was 1
                thr1 = tr1 * i2m;
                thr2 = tr2 * i2m;
                ox = fmaf(dx, t, ox); oy = fmaf(dy, t, oy); oz = fmaf(dz, t, oz);

                // material MLP, hidden dim split across the lane pair
                float st0=0.f, st1=0.f, st2=0.f;
                float dn0=0.f, dn1=0.f, dn2v=0.f;
                float rh0=0.f, rh1=0.f, rh2=0.f;
                const int j0 = half * 32;
                #pragma unroll 2
                for (int j = j0; j < j0 + 32; ++j) {
                    float pre = ox*Wf1[j] + oy*Wf1[HID+j] + oz*Wf1[2*HID+j]
                              + dx*Wf1[3*HID+j] + dy*Wf1[4*HID+j] + dz*Wf1[5*HID+j];
                    float f = tanh_fast(pre);
                    st0  = fmaf(f, Ws[j*3+0], st0);
                    st1  = fmaf(f, Ws[j*3+1], st1);
                    st2  = fmaf(f, Ws[j*3+2], st2);
                    dn0  = fmaf(f, Wdir[j*3+0], dn0);
                    dn1  = fmaf(f, Wdir[j*3+1], dn1);
                    dn2v = fmaf(f, Wdir[j*3+2], dn2v);
                    rh0  = fmaf(f, Wrho[j*3+0], rh0);
                    rh1  = fmaf(f, Wrho[j*3+1], rh1);
                    rh2  = fmaf(f, Wrho[j*3+2], rh2);
                }
                st0  += __shfl_xor(st0, 1, 64);
                st1  += __shfl_xor(st1, 1, 64);
                st2  += __shfl_xor(st2, 1, 64);
                dn0  += __shfl_xor(dn0, 1, 64);
                dn1  += __shfl_xor(dn1, 1, 64);
                dn2v += __shfl_xor(dn2v, 1, 64);
                rh0  += __shfl_xor(rh0, 1, 64);
                rh1  += __shfl_xor(rh1, 1, 64);
                rh2  += __shfl_xor(rh2, 1, 64);

                float stch = (ch == 0) ? st0 : ((ch == 1) ? st1 : st2);
                float sp = fminf(softplus_f(stch) / maj, 1.0f);
                if (u_scatter[m] < sp) {
                    float inr = 1.0f / (sqrtf(dn0*dn0 + dn1*dn1 + dn2v*dn2v) + EPSF);
                    dx = dn0*inr; dy = dn1*inr; dz = dn2v*inr;
                    float isp = 1.0f/(sp + EPSF);
                    thr0 *= isp * sigmoid_f(rh0);
                    thr1 *= isp * sigmoid_f(rh1);
                    thr2 *= isp * sigmoid_f(rh2);
                } else {
                    float iv = 1.0f/(1.0f - sp + EPSF);
                    thr0 *= iv; thr1 *= iv; thr2 *= iv;
                }
            }
        }
    }

    // ================= depth 1 (t = fars -> hit if delta>0) =================
    if (alive) {
        float a = dx*dx + dy*dy + dz*dz;
        float b = 2.0f*(dx*ox + dy*oy + dz*oz);
        float c = (ox*ox + oy*oy + oz*oz) - 1.0f;
        float delta = b*b - 4.0f*a*c;
        if (delta > 0.0f) {
            float sq    = sqrtf(delta);
            float nears = fmaxf((-b - sq) / (2.0f*a), 0.001f);
            float fars  = fmaxf((-b + sq) / (2.0f*a), 0.001f);
            float span  = fars - nears;

            float mx0, mx1, mx2;
            density_max3_half_d1(sT, ox,oy,oz, dx,dy,dz, nears, span,
                                 jitter + ((size_t)MTOT + m)*INDS + kbase, kbase,
                                 mx0,mx1,mx2);
            mx0 = fmaxf(mx0, __shfl_xor(mx0, 1, 64));
            mx1 = fmaxf(mx1, __shfl_xor(mx1, 1, 64));
            mx2 = fmaxf(mx2, __shfl_xor(mx2, 1, 64));

            float maj0 = fmaxf(softplus_f(mx0), 0.001f);
            float maj1 = fmaxf(softplus_f(mx1), 0.001f);
            float maj2 = fmaxf(softplus_f(mx2), 0.001f);
            float mmax = fmaxf(fmaxf(maj0, maj1), maj2);

            float den0 = __expf(-maj0*span)/(mmax+EPSF) + EPSF;
            float den1 = __expf(-maj1*span)/(mmax+EPSF) + EPSF;
            float den2 = __expf(-maj2*span)/(mmax+EPSF) + EPSF;
            float idm = 3.0f / (den0+den1+den2);
            float v0,v1,v2;
            env_logv(env_map, fmaf(dx,fars,ox), fmaf(dy,fars,oy), fmaf(dz,fars,oz), v0,v1,v2);
            rgb0 += thr0 * den0*idm*__expf(v0);
            rgb1 += thr1 * den1*idm*__expf(v1);
            rgb2 += thr2 * den2*idm*__expf(v2);
        }
    }

    // ---- reduction: each sub-ray duplicated x2 -> sum/256 == mean/128 ----
    float r0 = rgb0, r1 = rgb1, r2 = rgb2;
    #pragma unroll
    for (int off = 32; off > 0; off >>= 1) {
        r0 += __shfl_down(r0, off, 64);
        r1 += __shfl_down(r1, off, 64);
        r2 += __shfl_down(r2, off, 64);
    }
    int wave = tid >> 6;
    if ((tid & 63) == 0) {
        sred[wave][0] = r0; sred[wave][1] = r1; sred[wave][2] = r2;
    }
    __syncthreads();
    if (tid == 0) {
        out[ray*3+0] = (sred[0][0]+sred[1][0]+sred[2][0]+sred[3][0]) * (1.0f/256.0f);
        out[ray*3+1] = (sred[0][1]+sred[1][1]+sred[2][1]+sred[3][1]) * (1.0f/256.0f);
        out[ray*3+2] = (sred[0][2]+sred[1][2]+sred[2][2]+sred[3][2]) * (1.0f/256.0f);
    }
}

extern "C" void kernel_launch(void* const* d_in, const int* in_sizes, int n_in,
                              void* d_out, int out_size, void* d_ws, size_t ws_size,
                              hipStream_t stream) {
    const float* rays_o    = (const float*)d_in[0];
    const float* rays_d    = (const float*)d_in[1];
    const float* env_map   = (const float*)d_in[2];
    const float* Wd1       = (const float*)d_in[3];
    const float* Wd2       = (const float*)d_in[4];
    const float* Wf1       = (const float*)d_in[5];
    const float* Ws        = (const float*)d_in[6];
    const float* Wdir      = (const float*)d_in[7];
    const float* Wrho      = (const float*)d_in[8];
    const float* jitter    = (const float*)d_in[9];
    const float* u_t       = (const float*)d_in[10];
    const float* u_scatter = (const float*)d_in[11];
    const int*   channel   = (const int*)d_in[12];
    float* out = (float*)d_out;

    render_kernel<<<dim3(NRAYS), dim3(256), 0, stream>>>(
        rays_o, rays_d, env_map, Wd1, Wd2, Wf1, Ws, Wdir, Wrho,
        jitter, u_t, u_scatter, channel, out);
}

// Round 6
// 210.410 us; speedup vs baseline: 1.0389x; 1.0290x over previous
//
#include <hip/hip_runtime.h>
#include <math.h>

#define NRAYS 2048
#define TOT   128
#define INDS  16
#define HID   64
#define EPSF  1e-8f
#define MTOT  (NRAYS*TOT)

typedef float f32x2 __attribute__((ext_vector_type(2)));

__device__ __forceinline__ float softplus_f(float x) {
    return fmaxf(x, 0.0f) + __logf(1.0f + __expf(-fabsf(x)));
}
__device__ __forceinline__ float sigmoid_f(float x) {
    return 1.0f / (1.0f + __expf(-x));
}
__device__ __forceinline__ float tanh_fast(float x) {
    float e2 = __expf(2.0f * x);
    return 1.0f - 2.0f / (e2 + 1.0f);
}
__device__ __forceinline__ f32x2 pkmax(f32x2 a, f32x2 b) {
    f32x2 r; r.x = fmaxf(a.x, b.x); r.y = fmaxf(a.y, b.y); return r;
}

// Build the 8 jittered z samples for this half (kbase = 0 or 8).
#define MAKE_Z(jp, kbase, nears, span)                                        \
    const float4* jp4 = (const float4*)(jp);                                  \
    float4 jA = jp4[0], jB = jp4[1];                                          \
    float s16 = (span) * (1.0f/16.0f);                                        \
    float hs16 = 0.5f * s16;                                                  \
    f32x2 z01, z23, z45, z67;                                                 \
    z01.x = fmaf(jA.x, s16, fmaf((float)((kbase)+0)*(1.0f/15.0f), span, nears) - hs16); \
    z01.y = fmaf(jA.y, s16, fmaf((float)((kbase)+1)*(1.0f/15.0f), span, nears) - hs16); \
    z23.x = fmaf(jA.z, s16, fmaf((float)((kbase)+2)*(1.0f/15.0f), span, nears) - hs16); \
    z23.y = fmaf(jA.w, s16, fmaf((float)((kbase)+3)*(1.0f/15.0f), span, nears) - hs16); \
    z45.x = fmaf(jB.x, s16, fmaf((float)((kbase)+4)*(1.0f/15.0f), span, nears) - hs16); \
    z45.y = fmaf(jB.y, s16, fmaf((float)((kbase)+5)*(1.0f/15.0f), span, nears) - hs16); \
    z67.x = fmaf(jB.z, s16, fmaf((float)((kbase)+6)*(1.0f/15.0f), span, nears) - hs16); \
    z67.y = fmaf(jB.w, s16, fmaf((float)((kbase)+7)*(1.0f/15.0f), span, nears) - hs16);

// Inner body given A,B (pre-scaled by 1/2pi) and the 3 Wd2 weights.
#define DENSITY_J_BODY(Af, Bf, w20, w21, w22)                                 \
    {                                                                         \
        f32x2 A2 = {(Af),(Af)}, B2 = {(Bf),(Bf)};                             \
        f32x2 g01 = z01*B2 + A2;                                              \
        f32x2 g23 = z23*B2 + A2;                                              \
        f32x2 g45 = z45*B2 + A2;                                              \
        f32x2 g67 = z67*B2 + A2;                                              \
        f32x2 h01, h23, h45, h67;                                             \
        h01.x = __builtin_amdgcn_sinf(g01.x); h01.y = __builtin_amdgcn_sinf(g01.y); \
        h23.x = __builtin_amdgcn_sinf(g23.x); h23.y = __builtin_amdgcn_sinf(g23.y); \
        h45.x = __builtin_amdgcn_sinf(g45.x); h45.y = __builtin_amdgcn_sinf(g45.y); \
        h67.x = __builtin_amdgcn_sinf(g67.x); h67.y = __builtin_amdgcn_sinf(g67.y); \
        f32x2 W0 = {(w20),(w20)}, W1 = {(w21),(w21)}, W2 = {(w22),(w22)};     \
        a0_01 += h01*W0; a0_23 += h23*W0; a0_45 += h45*W0; a0_67 += h67*W0;   \
        a1_01 += h01*W1; a1_23 += h23*W1; a1_45 += h45*W1; a1_67 += h67*W1;   \
        a2_01 += h01*W2; a2_23 += h23*W2; a2_45 += h45*W2; a2_67 += h67*W2;   \
    }

#define DENSITY_EPILOG(mx0o, mx1o, mx2o)                                      \
    {                                                                         \
        f32x2 p0 = pkmax(pkmax(a0_01, a0_23), pkmax(a0_45, a0_67));           \
        f32x2 p1 = pkmax(pkmax(a1_01, a1_23), pkmax(a1_45, a1_67));           \
        f32x2 p2 = pkmax(pkmax(a2_01, a2_23), pkmax(a2_45, a2_67));           \
        mx0o = fmaxf(p0.x, p0.y);                                             \
        mx1o = fmaxf(p1.x, p1.y);                                             \
        mx2o = fmaxf(p2.x, p2.y);                                             \
    }

#define DECL_ACC                                                              \
    f32x2 a0_01 = {0.f,0.f}, a0_23 = {0.f,0.f}, a0_45 = {0.f,0.f}, a0_67 = {0.f,0.f}; \
    f32x2 a1_01 = {0.f,0.f}, a1_23 = {0.f,0.f}, a1_45 = {0.f,0.f}, a1_67 = {0.f,0.f}; \
    f32x2 a2_01 = {0.f,0.f}, a2_23 = {0.f,0.f}, a2_45 = {0.f,0.f}, a2_67 = {0.f,0.f};

// LDS table: 8 floats per j. q0={A,B,w20,w21}, q1={w22, w1x/2pi, w1y/2pi, w1z/2pi}
// Hot loops read ONLY LDS (in-order completion -> fine-grained lgkmcnt
// pipelining; r4 proved mixing s_load into the loop forces per-iter drains).
// unroll 2 (not 4): limits ds_read prefetch in flight to ~16 regs so the
// live set fits the (256,6) budget WITHOUT spilling (r5's (256,8) spilled
// 20 MB; r3's inline-A/B at (256,8) spilled 3.7 MB — 6/SIMD is the sweet spot).

__device__ __forceinline__ void density_max3_half_d0(
    const float* __restrict__ sT,
    float nears, float span, const float* __restrict__ jp, int kbase,
    float& mx0o, float& mx1o, float& mx2o)
{
    MAKE_Z(jp, kbase, nears, span)
    DECL_ACC
    #pragma unroll 2
    for (int j = 0; j < HID; ++j) {
        const float4* p = (const float4*)&sT[j*8];
        float4 q0 = p[0];
        float4 q1 = p[1];
        DENSITY_J_BODY(q0.x, q0.y, q0.z, q0.w, q1.x)
    }
    DENSITY_EPILOG(mx0o, mx1o, mx2o)
}

__device__ __forceinline__ void density_max3_half_d1(
    const float* __restrict__ sT,
    float ox, float oy, float oz, float dx, float dy, float dz,
    float nears, float span, const float* __restrict__ jp, int kbase,
    float& mx0o, float& mx1o, float& mx2o)
{
    MAKE_Z(jp, kbase, nears, span)
    DECL_ACC
    #pragma unroll 2
    for (int j = 0; j < HID; ++j) {
        const float4* p = (const float4*)&sT[j*8];
        float4 q0 = p[0];
        float4 q1 = p[1];
        float A = ox*q1.y + oy*q1.z + oz*q1.w;
        float B = dx*q1.y + dy*q1.z + dz*q1.w;
        DENSITY_J_BODY(A, B, q0.z, q0.w, q1.x)
    }
    DENSITY_EPILOG(mx0o, mx1o, mx2o)
}

__device__ __forceinline__ void env_logv(
    const float* __restrict__ env_map,
    float px, float py, float pz,
    float& v0, float& v1, float& v2)
{
    float theta = atan2f(px, -pz) * (1.0f/3.14159265358979323846f);
    float acv = (fabsf(py) <= 1.0f) ? acosf(py) : 0.0f;  // nan_to_num(arccos)
    float phi = 0.63661977236758134308f * acv - 1.0f;    // 2/pi
    float ixf = ((theta + 1.0f)*256.0f - 1.0f)*0.5f;
    float iyf = ((phi   + 1.0f)*128.0f - 1.0f)*0.5f;
    float x0f = floorf(ixf), y0f = floorf(iyf);
    float wx = ixf - x0f, wy = iyf - y0f;
    v0 = 0.f; v1 = 0.f; v2 = 0.f;
    auto tap = [&](float xc, float yc, float w) {
        if (xc >= 0.0f && xc < 256.0f && yc >= 0.0f && yc < 128.0f) {
            int xi = (int)xc, yi = (int)yc;
            const float* e = env_map + yi*256 + xi;
            v0 += w * e[0];
            v1 += w * e[128*256];
            v2 += w * e[2*128*256];
        }
    };
    tap(x0f,      y0f,      (1.0f-wx)*(1.0f-wy));
    tap(x0f+1.0f, y0f,      wx*(1.0f-wy));
    tap(x0f,      y0f+1.0f, (1.0f-wx)*wy);
    tap(x0f+1.0f, y0f+1.0f, wx*wy);
}

// 256 threads/block = 1 ray; lane pair (2s,2s+1) shares sub-ray s.
// (256,6): ~80-reg budget. Do NOT tighten to (256,8): the allocator gives
// up (VGPR=32) and spills MBs to scratch — seen twice (r3, r5).
__global__ __launch_bounds__(256, 6)
void render_kernel(const float* __restrict__ rays_o,
                   const float* __restrict__ rays_d,
                   const float* __restrict__ env_map,
                   const float* __restrict__ Wd1,
                   const float* __restrict__ Wd2,
                   const float* __restrict__ Wf1,
                   const float* __restrict__ Ws,
                   const float* __restrict__ Wdir,
                   const float* __restrict__ Wrho,
                   const float* __restrict__ jitter,
                   const float* __restrict__ u_t,
                   const float* __restrict__ u_scatter,
                   const int*   __restrict__ channel,
                   float* __restrict__ out)
{
    const int ray  = blockIdx.x;
    const int tid  = threadIdx.x;
    const int s    = tid >> 1;
    const int half = tid & 1;
    const int m    = ray * TOT + s;
    const int kbase = half * 8;

    __shared__ float sT[HID*8];
    __shared__ float sred[4][3];

    float ox = rays_o[ray*3+0], oy = rays_o[ray*3+1], oz = rays_o[ray*3+2];
    float dx = rays_d[ray*3+0], dy = rays_d[ray*3+1], dz = rays_d[ray*3+2];

    // ---- per-block table: A,B (block-uniform depth-0 geometry) + weights ----
    if (tid < HID) {
        const float INV2PI = 0.15915494309189535f;
        float w1x = Wd1[tid], w1y = Wd1[HID+tid], w1z = Wd1[2*HID+tid];
        float pw1x = w1x*INV2PI, pw1y = w1y*INV2PI, pw1z = w1z*INV2PI;
        float A = ox*pw1x + oy*pw1y + oz*pw1z;
        float B = dx*pw1x + dy*pw1y + dz*pw1z;
        float* p = &sT[tid*8];
        p[0] = A;            p[1] = B;
        p[2] = Wd2[3*tid];   p[3] = Wd2[3*tid+1];
        p[4] = Wd2[3*tid+2];
        p[5] = pw1x;         p[6] = pw1y;        p[7] = pw1z;
    }
    __syncthreads();

    float thr0 = 1.f, thr1 = 1.f, thr2 = 1.f;
    float rgb0 = 0.f, rgb1 = 0.f, rgb2 = 0.f;
    bool alive;

    // ================= depth 0 =================
    {
        float a = dx*dx + dy*dy + dz*dz;
        float b = 2.0f*(dx*ox + dy*oy + dz*oz);
        float c = (ox*ox + oy*oy + oz*oz) - 1.0f;
        float delta = b*b - 4.0f*a*c;
        alive = (delta > 0.0f);
        if (alive) {
            float sq    = sqrtf(delta);
            float nears = fmaxf((-b - sq) / (2.0f*a), 0.001f);
            float fars  = fmaxf((-b + sq) / (2.0f*a), 0.001f);
            float span  = fars - nears;

            float mx0, mx1, mx2;
            density_max3_half_d0(sT, nears, span,
                                 jitter + (size_t)m*INDS + kbase, kbase,
                                 mx0,mx1,mx2);
            mx0 = fmaxf(mx0, __shfl_xor(mx0, 1, 64));
            mx1 = fmaxf(mx1, __shfl_xor(mx1, 1, 64));
            mx2 = fmaxf(mx2, __shfl_xor(mx2, 1, 64));

            float maj0 = fmaxf(softplus_f(mx0), 0.001f);
            float maj1 = fmaxf(softplus_f(mx1), 0.001f);
            float maj2 = fmaxf(softplus_f(mx2), 0.001f);
            float mmax = fmaxf(fmaxf(maj0, maj1), maj2);

            int   ch  = channel[m];
            float maj = (ch == 0) ? maj0 : ((ch == 1) ? maj1 : maj2);
            float t   = -log1pf(-u_t[m]) / maj + nears;

            if (t >= fars) {
                float den0 = __expf(-maj0*span)/(mmax+EPSF) + EPSF;
                float den1 = __expf(-maj1*span)/(mmax+EPSF) + EPSF;
                float den2 = __expf(-maj2*span)/(mmax+EPSF) + EPSF;
                float idm = 3.0f / (den0+den1+den2);
                float v0,v1,v2;
                env_logv(env_map, fmaf(dx,fars,ox), fmaf(dy,fars,oy), fmaf(dz,fars,oz), v0,v1,v2);
                rgb0 = den0*idm*__expf(v0);
                rgb1 = den1*idm*__expf(v1);
                rgb2 = den2*idm*__expf(v2);
                alive = false;
            } else {
                float tn  = t - nears;
                float imm = 1.0f / mmax;
                float tr0 = __expf(-maj0*tn) * imm;
                float tr1 = __expf(-maj1*tn) * imm;
                float tr2 = __expf(-maj2*tn) * imm;
                float i2m = 3.0f / (maj0*tr0 + maj1*tr1 + maj2*tr2);
                thr0 = tr0 * i2m;   // thr was 1
                thr1 = tr1 * i2m;
                thr2 = tr2 * i2m;
                ox = fmaf(dx, t, ox); oy = fmaf(dy, t, oy); oz = fmaf(dz, t, oz);

                // material MLP, hidden dim split across the lane pair
                float st0=0.f, st1=0.f, st2=0.f;
                float dn0=0.f, dn1=0.f, dn2v=0.f;
                float rh0=0.f, rh1=0.f, rh2=0.f;
                const int j0 = half * 32;
                #pragma unroll 2
                for (int j = j0; j < j0 + 32; ++j) {
                    float pre = ox*Wf1[j] + oy*Wf1[HID+j] + oz*Wf1[2*HID+j]
                              + dx*Wf1[3*HID+j] + dy*Wf1[4*HID+j] + dz*Wf1[5*HID+j];
                    float f = tanh_fast(pre);
                    st0  = fmaf(f, Ws[j*3+0], st0);
                    st1  = fmaf(f, Ws[j*3+1], st1);
                    st2  = fmaf(f, Ws[j*3+2], st2);
                    dn0  = fmaf(f, Wdir[j*3+0], dn0);
                    dn1  = fmaf(f, Wdir[j*3+1], dn1);
                    dn2v = fmaf(f, Wdir[j*3+2], dn2v);
                    rh0  = fmaf(f, Wrho[j*3+0], rh0);
                    rh1  = fmaf(f, Wrho[j*3+1], rh1);
                    rh2  = fmaf(f, Wrho[j*3+2], rh2);
                }
                st0  += __shfl_xor(st0, 1, 64);
                st1  += __shfl_xor(st1, 1, 64);
                st2  += __shfl_xor(st2, 1, 64);
                dn0  += __shfl_xor(dn0, 1, 64);
                dn1  += __shfl_xor(dn1, 1, 64);
                dn2v += __shfl_xor(dn2v, 1, 64);
                rh0  += __shfl_xor(rh0, 1, 64);
                rh1  += __shfl_xor(rh1, 1, 64);
                rh2  += __shfl_xor(rh2, 1, 64);

                float stch = (ch == 0) ? st0 : ((ch == 1) ? st1 : st2);
                float sp = fminf(softplus_f(stch) / maj, 1.0f);
                if (u_scatter[m] < sp) {
                    float inr = 1.0f / (sqrtf(dn0*dn0 + dn1*dn1 + dn2v*dn2v) + EPSF);
                    dx = dn0*inr; dy = dn1*inr; dz = dn2v*inr;
                    float isp = 1.0f/(sp + EPSF);
                    thr0 *= isp * sigmoid_f(rh0);
                    thr1 *= isp * sigmoid_f(rh1);
                    thr2 *= isp * sigmoid_f(rh2);
                } else {
                    float iv = 1.0f/(1.0f - sp + EPSF);
                    thr0 *= iv; thr1 *= iv; thr2 *= iv;
                }
            }
        }
    }

    // ================= depth 1 (t = fars -> hit if delta>0) =================
    if (alive) {
        float a = dx*dx + dy*dy + dz*dz;
        float b = 2.0f*(dx*ox + dy*oy + dz*oz);
        float c = (ox*ox + oy*oy + oz*oz) - 1.0f;
        float delta = b*b - 4.0f*a*c;
        if (delta > 0.0f) {
            float sq    = sqrtf(delta);
            float nears = fmaxf((-b - sq) / (2.0f*a), 0.001f);
            float fars  = fmaxf((-b + sq) / (2.0f*a), 0.001f);
            float span  = fars - nears;

            float mx0, mx1, mx2;
            density_max3_half_d1(sT, ox,oy,oz, dx,dy,dz, nears, span,
                                 jitter + ((size_t)MTOT + m)*INDS + kbase, kbase,
                                 mx0,mx1,mx2);
            mx0 = fmaxf(mx0, __shfl_xor(mx0, 1, 64));
            mx1 = fmaxf(mx1, __shfl_xor(mx1, 1, 64));
            mx2 = fmaxf(mx2, __shfl_xor(mx2, 1, 64));

            float maj0 = fmaxf(softplus_f(mx0), 0.001f);
            float maj1 = fmaxf(softplus_f(mx1), 0.001f);
            float maj2 = fmaxf(softplus_f(mx2), 0.001f);
            float mmax = fmaxf(fmaxf(maj0, maj1), maj2);

            float den0 = __expf(-maj0*span)/(mmax+EPSF) + EPSF;
            float den1 = __expf(-maj1*span)/(mmax+EPSF) + EPSF;
            float den2 = __expf(-maj2*span)/(mmax+EPSF) + EPSF;
            float idm = 3.0f / (den0+den1+den2);
            float v0,v1,v2;
            env_logv(env_map, fmaf(dx,fars,ox), fmaf(dy,fars,oy), fmaf(dz,fars,oz), v0,v1,v2);
            rgb0 += thr0 * den0*idm*__expf(v0);
            rgb1 += thr1 * den1*idm*__expf(v1);
            rgb2 += thr2 * den2*idm*__expf(v2);
        }
    }

    // ---- reduction: each sub-ray duplicated x2 -> sum/256 == mean/128 ----
    float r0 = rgb0, r1 = rgb1, r2 = rgb2;
    #pragma unroll
    for (int off = 32; off > 0; off >>= 1) {
        r0 += __shfl_down(r0, off, 64);
        r1 += __shfl_down(r1, off, 64);
        r2 += __shfl_down(r2, off, 64);
    }
    int wave = tid >> 6;
    if ((tid & 63) == 0) {
        sred[wave][0] = r0; sred[wave][1] = r1; sred[wave][2] = r2;
    }
    __syncthreads();
    if (tid == 0) {
        out[ray*3+0] = (sred[0][0]+sred[1][0]+sred[2][0]+sred[3][0]) * (1.0f/256.0f);
        out[ray*3+1] = (sred[0][1]+sred[1][1]+sred[2][1]+sred[3][1]) * (1.0f/256.0f);
        out[ray*3+2] = (sred[0][2]+sred[1][2]+sred[2][2]+sred[3][2]) * (1.0f/256.0f);
    }
}

extern "C" void kernel_launch(void* const* d_in, const int* in_sizes, int n_in,
                              void* d_out, int out_size, void* d_ws, size_t ws_size,
                              hipStream_t stream) {
    const float* rays_o    = (const float*)d_in[0];
    const float* rays_d    = (const float*)d_in[1];
    const float* env_map   = (const float*)d_in[2];
    const float* Wd1       = (const float*)d_in[3];
    const float* Wd2       = (const float*)d_in[4];
    const float* Wf1       = (const float*)d_in[5];
    const float* Ws        = (const float*)d_in[6];
    const float* Wdir      = (const float*)d_in[7];
    const float* Wrho      = (const float*)d_in[8];
    const float* jitter    = (const float*)d_in[9];
    const float* u_t       = (const float*)d_in[10];
    const float* u_scatter = (const float*)d_in[11];
    const int*   channel   = (const int*)d_in[12];
    float* out = (float*)d_out;

    render_kernel<<<dim3(NRAYS), dim3(256), 0, stream>>>(
        rays_o, rays_d, env_map, Wd1, Wd2, Wf1, Ws, Wdir, Wrho,
        jitter, u_t, u_scatter, channel, out);
}